// Round 4
// baseline (134.293 us; speedup 1.0000x reference)
//
#include <hip/hip_runtime.h>

// DETR-style post-process, single fused persistent kernel.
// Outputs (flat f32, concatenated): scores[B*Q] | labels[B*Q] | boxes[B*Q*4] | keep[B*Q]
//
// Grid: 256 blocks x 1024 threads. 8 sibling blocks per image (b = bid&31, sb = bid>>5,
// so siblings land on the same XCD under the bid%8 round-robin heuristic).
// Phases, separated by per-image 8-block device-scope barriers:
//   A: softmax score/label + box convert/scale (chip-wide, HBM-bound)
//   B: counting rank (stable descending argsort) -> sorted boxes in ws
//   C: suppression bitmask tiles (136 tri-tiles/image over 128 wave-slots)
//   D: block sb==0 per image: 16-chunk greedy scan (the only serial part)

constexpr int kB  = 32;
constexpr int kQ  = 1024;
constexpr int kNC = 256;
constexpr int kBQ = kB * kQ;
constexpr float kIouThr = 0.5f;

typedef unsigned long long u64;
typedef unsigned int u32;

struct __align__(8) Bar { u32 cnt; u32 gen; };

// Sense/generation barrier among nb blocks. Safe for repeated use; state zeroed
// each call by a memset node, and cnt returns to 0 after every barrier.
__device__ __forceinline__ void image_barrier(Bar* bar, u32 nb) {
  __syncthreads();
  if (threadIdx.x == 0) {
    u32 g = __hip_atomic_load(&bar->gen, __ATOMIC_RELAXED, __HIP_MEMORY_SCOPE_AGENT);
    u32 a = __hip_atomic_fetch_add(&bar->cnt, 1u, __ATOMIC_ACQ_REL, __HIP_MEMORY_SCOPE_AGENT);
    if (a == nb - 1u) {
      __hip_atomic_store(&bar->cnt, 0u, __ATOMIC_RELAXED, __HIP_MEMORY_SCOPE_AGENT);
      __hip_atomic_store(&bar->gen, g + 1u, __ATOMIC_RELEASE, __HIP_MEMORY_SCOPE_AGENT);
    } else {
      u32 cur;
      do {
        __builtin_amdgcn_s_sleep(2);
        cur = __hip_atomic_load(&bar->gen, __ATOMIC_ACQUIRE, __HIP_MEMORY_SCOPE_AGENT);
      } while (cur == g);
    }
  }
  __syncthreads();
}

// IoU > thr with numpy-identical op ordering (no FMA contraction, exact division).
__device__ __forceinline__ bool iou_gt(const float4& a, float aa,
                                       const float4& b, float ba) {
  float lx = fmaxf(a.x, b.x);
  float ly = fmaxf(a.y, b.y);
  float rx = fminf(a.z, b.z);
  float ry = fminf(a.w, b.w);
  float w  = fmaxf(__fsub_rn(rx, lx), 0.0f);
  float h  = fmaxf(__fsub_rn(ry, ly), 0.0f);
  float inter = __fmul_rn(w, h);
  float uni   = __fsub_rn(__fadd_rn(aa, ba), inter);
  float iou   = __fdiv_rn(inter, fmaxf(uni, 1e-9f));
  return iou > kIouThr;
}

__global__ void __launch_bounds__(1024, 4) k_fused(
    const float* __restrict__ logits, const float* __restrict__ pboxes,
    const int* __restrict__ ts, float* out,
    u64* maskT, u32* order, float4* sbox, float* sarea, Bar* bars) {

  const int tid  = (int)threadIdx.x;
  const int bid  = (int)blockIdx.x;
  const int b    = bid & 31;        // image
  const int sb   = bid >> 5;        // sibling id 0..7 (same XCD as other sibs of b)
  const int lane = tid & 63;
  const int wv   = tid >> 6;        // 0..15

  __shared__ u64   keysS[kQ];       // 8 KB
  __shared__ int   counts[128];     // 0.5 KB
  __shared__ float4 iboxS[16][64];  // 16 KB
  __shared__ float  iareaS[16][64]; // 4 KB
  __shared__ u64   aliveS[16];      // 128 B

  // ---------------- Phase A: scores / labels / boxes ----------------
  {
    float ih = (float)ts[b * 2 + 0];
    float iw = (float)ts[b * 2 + 1];
    for (int k = 0; k < 8; ++k) {
      int q  = sb * 128 + wv * 8 + k;
      int gq = b * kQ + q;
      float4 v = reinterpret_cast<const float4*>(logits)[gq * (kNC / 4) + lane];

      float m = fmaxf(fmaxf(v.x, v.y), fmaxf(v.z, v.w));
      for (int off = 32; off > 0; off >>= 1) m = fmaxf(m, __shfl_xor(m, off, 64));

      // foreground (first 255 classes) max + argmax, first-occurrence tie-break
      float fw = (lane == 63) ? -INFINITY : v.w;
      float fm = v.x; int fi = lane * 4;
      if (v.y > fm) { fm = v.y; fi = lane * 4 + 1; }
      if (v.z > fm) { fm = v.z; fi = lane * 4 + 2; }
      if (fw  > fm) { fm = fw;  fi = lane * 4 + 3; }
      for (int off = 32; off > 0; off >>= 1) {
        float om = __shfl_xor(fm, off, 64);
        int   oi = __shfl_xor(fi, off, 64);
        if (om > fm || (om == fm && oi < fi)) { fm = om; fi = oi; }
      }

      float s = expf(v.x - m) + expf(v.y - m) + expf(v.z - m) + expf(v.w - m);
      for (int off = 32; off > 0; off >>= 1) s += __shfl_xor(s, off, 64);

      if (lane == 0) {
        out[gq]       = expf(fm - m) / s;
        out[kBQ + gq] = (float)fi;

        float4 pb = reinterpret_cast<const float4*>(pboxes)[gq];
        float hw = __fmul_rn(0.5f, pb.z);
        float hh = __fmul_rn(0.5f, pb.w);
        float x0 = __fmul_rn(__fsub_rn(pb.x, hw), iw);
        float y0 = __fmul_rn(__fsub_rn(pb.y, hh), ih);
        float x1 = __fmul_rn(__fadd_rn(pb.x, hw), iw);
        float y1 = __fmul_rn(__fadd_rn(pb.y, hh), ih);
        reinterpret_cast<float4*>(out + 2 * kBQ)[gq] = make_float4(x0, y0, x1, y1);
      }
    }
  }
  image_barrier(&bars[b], 8);

  // ---------------- Phase B: counting rank ----------------
  {
    keysS[tid] = ((u64)(~__float_as_uint(out[b * kQ + tid])) << 32) | (u32)tid;
    if (tid < 128) counts[tid] = 0;
    __syncthreads();

    int jj = tid & 127;
    int j  = sb * 128 + jj;
    u64 kj = keysS[j];
    int base = (tid >> 7) * 128;
    int cnt = 0;
    #pragma unroll 4
    for (int k = 0; k < 128; ++k) cnt += (int)(keysS[base + k] < kj);
    atomicAdd(&counts[jj], cnt);
    __syncthreads();

    if (tid < 128) {
      int j2 = sb * 128 + tid;
      int r  = counts[tid];
      float4 bx = reinterpret_cast<const float4*>(out + 2 * kBQ)[b * kQ + j2];
      order[b * kQ + r] = (u32)j2;
      sbox[b * kQ + r]  = bx;
      sarea[b * kQ + r] = __fmul_rn(__fsub_rn(bx.z, bx.x), __fsub_rn(bx.w, bx.y));
    }
  }
  image_barrier(&bars[b], 8);

  // ---------------- Phase C: mask tiles ----------------
  {
    int slot = sb * 16 + wv;                    // 0..127 wave-slots per image
    for (int r = slot; r < 136; r += 128) {     // 136 tri-tiles (jb >= c)
      int jb = (int)((sqrtf((float)(8 * r + 1)) - 1.0f) * 0.5f);
      while ((jb + 1) * (jb + 2) / 2 <= r) ++jb;
      while (jb * (jb + 1) / 2 > r) --jb;
      int c = r - jb * (jb + 1) / 2;

      iboxS[wv][lane]  = sbox[b * kQ + c * 64 + lane];
      iareaS[wv][lane] = sarea[b * kQ + c * 64 + lane];
      // wave-private LDS slice: in-wave LDS ordering suffices, no block barrier.

      int j = jb * 64 + lane;
      float4 bj = sbox[b * kQ + j];
      float  aj = sarea[b * kQ + j];

      u32 wlo = 0, whi = 0;
      if (c < jb) {                              // full tile: every i < j
        #pragma unroll 4
        for (int l = 0; l < 32; ++l)
          wlo |= ((u32)iou_gt(iboxS[wv][l], iareaS[wv][l], bj, aj)) << l;
        #pragma unroll 4
        for (int l = 0; l < 32; ++l)
          whi |= ((u32)iou_gt(iboxS[wv][l + 32], iareaS[wv][l + 32], bj, aj)) << l;
      } else {                                   // diagonal: strict l < lane
        #pragma unroll 4
        for (int l = 0; l < 32; ++l)
          wlo |= ((u32)((l < lane) && iou_gt(iboxS[wv][l], iareaS[wv][l], bj, aj))) << l;
        #pragma unroll 4
        for (int l = 0; l < 32; ++l)
          whi |= ((u32)((l + 32 < lane) && iou_gt(iboxS[wv][l + 32], iareaS[wv][l + 32], bj, aj))) << l;
      }
      maskT[(b * 16 + c) * kQ + j] = ((u64)whi << 32) | wlo;
    }
  }
  image_barrier(&bars[b], 8);

  // ---------------- Phase D: greedy scan (block sb==0 only) ----------------
  if (sb != 0) return;
  {
    bool supp = false;
    u64 wcur = maskT[(b * 16 + 0) * kQ + tid];

    for (int c = 0; c < 16; ++c) {
      u64 wnext = (c < 15) ? maskT[(b * 16 + c + 1) * kQ + tid] : 0ull;

      if (wv == c) {
        u64 prior = __ballot(supp);
        u32 dlo = (u32)wcur, dhi = (u32)(wcur >> 32);
        u64 alive = 0ull;
        u64 todo = ~prior;                      // candidates in rank order
        while (todo) {
          int l = __builtin_ctzll(todo);
          todo &= todo - 1ull;
          u64 w = ((u64)(u32)__builtin_amdgcn_readlane((int)dhi, l) << 32)
                |  (u64)(u32)__builtin_amdgcn_readlane((int)dlo, l);
          if ((w & alive) == 0ull) alive |= 1ull << l;
        }
        if (lane == 0) aliveS[c] = alive;
        supp = ((alive >> lane) & 1ull) == 0ull;
      }
      __syncthreads();
      if (wv > c) supp = supp || ((wcur & aliveS[c]) != 0ull);
      wcur = wnext;
    }

    u32 oj = order[b * kQ + tid];
    out[6 * kBQ + b * kQ + (int)oj] = supp ? 0.0f : 1.0f;
  }
}

extern "C" void kernel_launch(void* const* d_in, const int* in_sizes, int n_in,
                              void* d_out, int out_size, void* d_ws, size_t ws_size,
                              hipStream_t stream) {
  const float* logits = (const float*)d_in[0];
  const float* pboxes = (const float*)d_in[1];
  const int*   ts     = (const int*)d_in[2];
  float* out = (float*)d_out;

  // ws layout: maskT 4MB | order 128KB | sbox 512KB | sarea 128KB | bars 256B
  char* ws = (char*)d_ws;
  u64*    maskT = (u64*)ws;
  u32*    order = (u32*)(ws + (4 << 20));
  float4* sbox  = (float4*)(ws + (4 << 20) + (128 << 10));
  float*  sarea = (float*)(ws + (4 << 20) + (640 << 10));
  Bar*    bars  = (Bar*)(ws + (4 << 20) + (768 << 10));

  hipMemsetAsync(bars, 0, kB * sizeof(Bar), stream);
  k_fused<<<dim3(256), dim3(1024), 0, stream>>>(logits, pboxes, ts, out,
                                                maskT, order, sbox, sarea, bars);
}

// Round 5
// 85.729 us; speedup vs baseline: 1.5665x; 1.5665x over previous
//
#include <hip/hip_runtime.h>

// DETR-style post-process: softmax scores/labels + box scale + per-image greedy NMS.
// Outputs (flat f32, concatenated): scores[B*Q] | labels[B*Q] | boxes[B*Q*4] | keep[B*Q]
//
// Pipeline (4 graph nodes):
//  k_score_box : per-(b,q) wave softmax/argmax + box conversion       (HBM-bound)
//  k_rank      : counting-rank (stable descending argsort) -> ws      (VALU, cheap)
//  k_mask      : suppression bitmask, 4 tri-tiles per 256-thr block   (VALU-bound)
//  k_scan      : 1 wave/image, barrier-free ballot greedy scan        (serial floor)

constexpr int kB  = 32;
constexpr int kQ  = 1024;
constexpr int kNC = 256;
constexpr int kBQ = kB * kQ;
constexpr float kIouThr = 0.5f;

typedef unsigned long long u64;
typedef unsigned int u32;

// IoU > thr with numpy-identical op ordering (no FMA contraction, exact division).
__device__ __forceinline__ bool iou_gt(const float4& a, float aa,
                                       const float4& b, float ba) {
  float lx = fmaxf(a.x, b.x);
  float ly = fmaxf(a.y, b.y);
  float rx = fminf(a.z, b.z);
  float ry = fminf(a.w, b.w);
  float w  = fmaxf(__fsub_rn(rx, lx), 0.0f);
  float h  = fmaxf(__fsub_rn(ry, ly), 0.0f);
  float inter = __fmul_rn(w, h);
  float uni   = __fsub_rn(__fadd_rn(aa, ba), inter);
  float iou   = __fdiv_rn(inter, fmaxf(uni, 1e-9f));
  return iou > kIouThr;
}

// One wave (64 lanes) per (b,q): 256 logits -> softmax score/label; box cxcywh->xyxy*scale.
// max over all 256 = fmax(fg_max over 255, logit[255]) -> saves one full reduction.
__global__ void k_score_box(const float* __restrict__ logits,
                            const float* __restrict__ pboxes,
                            const int* __restrict__ ts,
                            float* __restrict__ out) {
  int gw   = (int)((blockIdx.x * blockDim.x + threadIdx.x) >> 6);
  int lane = (int)(threadIdx.x & 63);
  if (gw >= kBQ) return;

  float4 v = reinterpret_cast<const float4*>(logits)[gw * (kNC / 4) + lane];

  // foreground (first 255 classes) max + argmax, first-occurrence tie-break
  float fw = (lane == 63) ? -INFINITY : v.w;
  float fm = v.x; int fi = lane * 4;
  if (v.y > fm) { fm = v.y; fi = lane * 4 + 1; }
  if (v.z > fm) { fm = v.z; fi = lane * 4 + 2; }
  if (fw  > fm) { fm = fw;  fi = lane * 4 + 3; }
  for (int off = 32; off > 0; off >>= 1) {
    float om = __shfl_xor(fm, off, 64);
    int   oi = __shfl_xor(fi, off, 64);
    if (om > fm || (om == fm && oi < fi)) { fm = om; fi = oi; }
  }

  float last = __shfl(v.w, 63, 64);     // logit of class 255 (bg)
  float m = fmaxf(fm, last);            // max over all 256 (exact, same value as before)

  float s = expf(v.x - m) + expf(v.y - m) + expf(v.z - m) + expf(v.w - m);
  for (int off = 32; off > 0; off >>= 1) s += __shfl_xor(s, off, 64);

  if (lane == 0) {
    out[gw]        = expf(fm - m) / s;
    out[kBQ + gw]  = (float)fi;

    float4 pb = reinterpret_cast<const float4*>(pboxes)[gw];
    int bi = gw >> 10;
    float ih = (float)ts[bi * 2 + 0];
    float iw = (float)ts[bi * 2 + 1];
    float hw = __fmul_rn(0.5f, pb.z);
    float hh = __fmul_rn(0.5f, pb.w);
    float x0 = __fmul_rn(__fsub_rn(pb.x, hw), iw);
    float y0 = __fmul_rn(__fsub_rn(pb.y, hh), ih);
    float x1 = __fmul_rn(__fadd_rn(pb.x, hw), iw);
    float y1 = __fmul_rn(__fadd_rn(pb.y, hh), ih);
    reinterpret_cast<float4*>(out + 2 * kBQ)[gw] = make_float4(x0, y0, x1, y1);
  }
}

// Counting rank: rank_j = #{k : key_k < key_j}, key = (~score_bits)<<32 | idx.
// Exactly reproduces stable argsort(-scores). Scatters sorted boxes/areas/order to ws.
__global__ void __launch_bounds__(256) k_rank(const float* __restrict__ out,
                                              u32* __restrict__ order,
                                              float4* __restrict__ sbox,
                                              float* __restrict__ sarea) {
  __shared__ u64 keys[kQ];
  const int b = (int)blockIdx.x, sb = (int)blockIdx.y, tid = (int)threadIdx.x;

  for (int t = tid; t < kQ; t += 256) {
    u32 s = __float_as_uint(out[b * kQ + t]);       // scores > 0 -> bit-monotone
    keys[t] = ((u64)(~s) << 32) | (u32)t;
  }
  __syncthreads();

  const int j = sb * 256 + tid;
  const u64 kj = keys[j];
  int cnt = 0;
  #pragma unroll 4
  for (int k = 0; k < kQ; k += 2) {                 // broadcast LDS reads
    cnt += (int)(keys[k] < kj) + (int)(keys[k + 1] < kj);
  }

  float4 bx = reinterpret_cast<const float4*>(out + 2 * kBQ)[b * kQ + j];
  order[b * kQ + cnt] = (u32)j;
  sbox[b * kQ + cnt]  = bx;
  sarea[b * kQ + cnt] = __fmul_rn(__fsub_rn(bx.z, bx.x), __fsub_rn(bx.w, bx.y));
}

// Suppression bitmask, column form: maskT[b][c][j] bit l = (i=c*64+l < j) && IoU(i,j)>thr.
// 4 waves/block, one 64x64 tri-tile per wave: grid (32, 34), r = by*4+wv in [0,136).
__global__ void __launch_bounds__(256) k_mask(const float4* __restrict__ sbox,
                                              const float* __restrict__ sarea,
                                              u64* __restrict__ maskT) {
  const int b = (int)blockIdx.x;
  const int wv = (int)(threadIdx.x >> 6), lane = (int)(threadIdx.x & 63);
  const int r = (int)blockIdx.y * 4 + wv;           // 0..135, all valid

  // linear tri index -> (jb, c), jb >= c
  int jb = (int)((sqrtf((float)(8 * r + 1)) - 1.0f) * 0.5f);
  while ((jb + 1) * (jb + 2) / 2 <= r) ++jb;
  while (jb * (jb + 1) / 2 > r) --jb;
  const int c = r - jb * (jb + 1) / 2;

  __shared__ float4 iboxS[4][64];
  __shared__ float  iareaS[4][64];
  iboxS[wv][lane]  = sbox[b * kQ + c * 64 + lane];
  iareaS[wv][lane] = sarea[b * kQ + c * 64 + lane];
  // wave-private LDS slice: in-wave ds ordering suffices, no block barrier.

  const int j = jb * 64 + lane;
  const float4 bj = sbox[b * kQ + j];
  const float  aj = sarea[b * kQ + j];

  u32 wlo = 0, whi = 0;
  if (c < jb) {                                     // full tile: every i < j
    #pragma unroll 4
    for (int l = 0; l < 32; ++l)
      wlo |= ((u32)iou_gt(iboxS[wv][l], iareaS[wv][l], bj, aj)) << l;
    #pragma unroll 4
    for (int l = 0; l < 32; ++l)
      whi |= ((u32)iou_gt(iboxS[wv][l + 32], iareaS[wv][l + 32], bj, aj)) << l;
  } else {                                          // diagonal: strict l < lane
    #pragma unroll 4
    for (int l = 0; l < 32; ++l)
      wlo |= ((u32)((l < lane) && iou_gt(iboxS[wv][l], iareaS[wv][l], bj, aj))) << l;
    #pragma unroll 4
    for (int l = 0; l < 32; ++l)
      whi |= ((u32)((l + 32 < lane) && iou_gt(iboxS[wv][l + 32], iareaS[wv][l + 32], bj, aj))) << l;
  }
  maskT[(b * 16 + c) * kQ + j] = ((u64)whi << 32) | wlo;
}

// Barrier-free greedy scan: one wave per image. Stage the image's 128KB maskT
// in LDS, then per chunk c: ballot-driven greedy (one iteration per KEPT box:
// alive only grows, so any lane with (diag & alive)!=0 is suppressed forever),
// then fold alive into later chunks with one LDS AND per (lane, chunk).
__global__ void __launch_bounds__(256) k_scan(const u64* __restrict__ maskT,
                                              const u32* __restrict__ order,
                                              float* __restrict__ out) {
  __shared__ u64 lm[16 * kQ];                       // 128 KB (1 block/CU; 32 blocks)
  const int b = (int)blockIdx.x, tid = (int)threadIdx.x;

  const uint4* src = (const uint4*)(maskT + (size_t)b * 16 * kQ);
  uint4* dst = (uint4*)lm;
  #pragma unroll 4
  for (int t = tid; t < 16 * kQ / 2; t += 256) dst[t] = src[t];
  __syncthreads();
  if (tid >= 64) return;                            // waves 1-3 only helped copy
  const int lane = tid;

  u32 sbits = 0;                                    // bit k: j=k*64+lane suppressed
  u32 keepbits = 0;
  for (int c = 0; c < 16; ++c) {
    u64 d = lm[c * kQ + c * 64 + lane];             // diag word (bits i<lane only)
    u64 todo = ~__ballot(((sbits >> c) & 1u) != 0u);
    u64 alive = 0ull;
    while (true) {
      u64 bal = __ballot((d & alive) == 0ull) & todo;
      if (bal == 0ull) break;
      int l = __builtin_ctzll(bal);                 // lowest eligible rank
      alive |= 1ull << l;
      todo &= ~((2ull << l) - 1ull);                // lanes <l proven suppressed; l kept
    }
    keepbits |= ((u32)((alive >> lane) & 1ull)) << c;
    for (int k = c + 1; k < 16; ++k) {              // fold kept set into later chunks
      u64 w = lm[c * kQ + k * 64 + lane];
      if ((w & alive) != 0ull) sbits |= 1u << k;
    }
  }

  const u32* ord = order + b * kQ;
  float* kout = out + 6 * kBQ + b * kQ;
  #pragma unroll
  for (int k = 0; k < 16; ++k) {
    u32 oj = ord[k * 64 + lane];
    kout[oj] = ((keepbits >> k) & 1u) ? 1.0f : 0.0f;
  }
}

extern "C" void kernel_launch(void* const* d_in, const int* in_sizes, int n_in,
                              void* d_out, int out_size, void* d_ws, size_t ws_size,
                              hipStream_t stream) {
  const float* logits = (const float*)d_in[0];
  const float* pboxes = (const float*)d_in[1];
  const int*   ts     = (const int*)d_in[2];
  float* out = (float*)d_out;

  // ws layout (≈4.75 MB): maskT 4MB | order 128KB | sbox 512KB | sarea 128KB
  char* ws = (char*)d_ws;
  u64*    maskT = (u64*)ws;
  u32*    order = (u32*)(ws + (4 << 20));
  float4* sbox  = (float4*)(ws + (4 << 20) + (128 << 10));
  float*  sarea = (float*)(ws + (4 << 20) + (640 << 10));

  dim3 g1(kBQ / 4), t1(256);
  k_score_box<<<g1, t1, 0, stream>>>(logits, pboxes, ts, out);

  dim3 g2(kB, kQ / 256), t2(256);
  k_rank<<<g2, t2, 0, stream>>>(out, order, sbox, sarea);

  dim3 g3(kB, 34), t3(256);
  k_mask<<<g3, t3, 0, stream>>>(sbox, sarea, maskT);

  k_scan<<<kB, 256, 0, stream>>>(maskT, order, out);
}